// Round 11
// baseline (435.622 us; speedup 1.0000x reference)
//
#include <hip/hip_runtime.h>
#include <hip/hip_bf16.h>

#define N_GRAPHS 128
#define BN_EPS 1e-5f
#define CHUNK 8192
#define NBU 512            // padded bucket count (actual NB = ceil(N/128) = 391)
#define CAP 8192           // per-bucket edge capacity (mean 4096, sd ~64)

typedef short bf16x8 __attribute__((ext_vector_type(8)));
typedef short s16x4 __attribute__((ext_vector_type(4)));
typedef float f32x4 __attribute__((ext_vector_type(4)));

__device__ __forceinline__ unsigned short f2b(float f) {   // f32 -> bf16 RNE
    unsigned int u = __builtin_bit_cast(unsigned int, f);
    u += 0x7FFFu + ((u >> 16) & 1u);
    return (unsigned short)(u >> 16);
}
__device__ __forceinline__ float b2f_lo(unsigned int p) {
    return __builtin_bit_cast(float, p << 16);
}
__device__ __forceinline__ float b2f_hi(unsigned int p) {
    return __builtin_bit_cast(float, p & 0xFFFF0000u);
}
__device__ __forceinline__ unsigned int packrelu(float a, float b) {
    return (unsigned int)f2b(fmaxf(a, 0.f)) | ((unsigned int)f2b(fmaxf(b, 0.f)) << 16);
}

// ---------------- K1: per-chunk bucket binning (no global scatter atomics) ----------------
__global__ __launch_bounds__(512) void bin_chunks(const int* __restrict__ src,
                                                  const int* __restrict__ dst,
                                                  unsigned int* __restrict__ bpairs,
                                                  int* __restrict__ cnts,
                                                  int* __restrict__ cbase,
                                                  int* __restrict__ btot, int E) {
    __shared__ int lhist[NBU], lscan[NBU], lfill[NBU];
    int tid = threadIdx.x;
    int c0 = blockIdx.x * CHUNK;
    int ecnt = min(CHUNK, E - c0);
    lhist[tid] = 0;
    __syncthreads();
    for (int i = tid; i < ecnt; i += 512)
        atomicAdd(&lhist[((unsigned)dst[c0 + i]) >> 7], 1);
    __syncthreads();
    int orig = lhist[tid];
    atomicAdd(&btot[tid], orig);
    lscan[tid] = orig;
    __syncthreads();
    for (int off = 1; off < NBU; off <<= 1) {
        int t = (tid >= off) ? lscan[tid - off] : 0;
        __syncthreads();
        lscan[tid] += t;
        __syncthreads();
    }
    int excl = lscan[tid] - orig;
    cnts[blockIdx.x * NBU + tid] = orig;
    cbase[blockIdx.x * NBU + tid] = excl;
    lfill[tid] = 0;
    __syncthreads();
    lscan[tid] = excl;
    __syncthreads();
    for (int i = tid; i < ecnt; i += 512) {
        int d = dst[c0 + i], s = src[c0 + i];
        int b = ((unsigned)d) >> 7;
        int pos = lscan[b] + atomicAdd(&lfill[b], 1);
        bpairs[c0 + pos] = ((unsigned)(d & 127) << 25) | (unsigned)s;
    }
}

// ---------------- K2: per-bucket CSR finalize (direct global scatter, 38 KB LDS) --------
__global__ __launch_bounds__(256) void bucket_csr(const unsigned int* __restrict__ bpairs,
                                                  const int* __restrict__ cnts,
                                                  const int* __restrict__ cbase,
                                                  const int* __restrict__ btot,
                                                  int* __restrict__ rowp,
                                                  int* __restrict__ degarr,
                                                  float* __restrict__ dinv,
                                                  int* __restrict__ csr,
                                                  int nchunks, int N) {
    __shared__ unsigned int lpr[CAP];
    __shared__ int ccnt[256], cofs[256], cb[256];
    __shared__ int lhist[128], lofs[128], lfill[128];
    __shared__ int rsum[256];
    int tid = threadIdx.x;
    int b = blockIdx.x;

    // bucket base = prefix sum of btot[0..b); total = btot[b]
    int t1 = (tid < b) ? btot[tid] : 0;
    int t2 = (tid + 256 < b) ? btot[tid + 256] : 0;
    rsum[tid] = t1 + t2;
    __syncthreads();
    for (int off2 = 128; off2 > 0; off2 >>= 1) {
        if (tid < off2) rsum[tid] += rsum[tid + off2];
        __syncthreads();
    }
    int bb = rsum[0];
    int total = btot[b];
    if (total > CAP) total = CAP;
    __syncthreads();

    ccnt[tid] = (tid < nchunks) ? cnts[tid * NBU + b] : 0;
    cb[tid]   = (tid < nchunks) ? cbase[tid * NBU + b] : 0;
    cofs[tid] = ccnt[tid];
    __syncthreads();
    int orig = cofs[tid];
    for (int off = 1; off < 256; off <<= 1) {
        int t = (tid >= off) ? cofs[tid - off] : 0;
        __syncthreads();
        cofs[tid] += t;
        __syncthreads();
    }
    int o = cofs[tid] - orig;
    if (tid < nchunks) {
        int len = ccnt[tid];
        const unsigned int* p = bpairs + (size_t)tid * CHUNK + cb[tid];
        for (int i = 0; i < len; ++i) {
            int q = o + i;
            if (q < CAP) lpr[q] = p[i];
        }
    }
    if (tid < 128) { lhist[tid] = 0; lfill[tid] = 0; }
    __syncthreads();
    for (int i = tid; i < total; i += 256)
        atomicAdd(&lhist[lpr[i] >> 25], 1);
    __syncthreads();
    if (tid < 128) lofs[tid] = lhist[tid];
    __syncthreads();
    for (int off = 1; off < 128; off <<= 1) {
        int t = 0;
        if (tid < 128 && tid >= off) t = lofs[tid - off];
        __syncthreads();
        if (tid < 128) lofs[tid] += t;
        __syncthreads();
    }
    if (tid < 128) {
        int v = b * 128 + tid;
        if (v < N) {
            int dg = lhist[tid];
            degarr[v] = dg;
            rowp[v] = bb + lofs[tid] - dg;
            dinv[v] = rsqrtf((float)(dg + 1));
        }
    }
    __syncthreads();
    // scatter FINAL csr values directly to global (block-private ~16 KB window -> L2)
    for (int i = tid; i < total; i += 256) {
        unsigned int pr = lpr[i];
        int dl = pr >> 25;
        int pos = lofs[dl] - lhist[dl] + atomicAdd(&lfill[dl], 1);
        if (pos < CAP) csr[bb + pos] = (int)(pr & 0x1FFFFFFu);
    }
}

// ---------------- W0 prep (no BN) + graph counts (block 64) ----------------
__global__ __launch_bounds__(256) void prep_w0(const float* __restrict__ W,
                                               unsigned short* __restrict__ Wp,
                                               const int* __restrict__ batch,
                                               int* __restrict__ gcnt, int N) {
    int tid = threadIdx.x;
    if (blockIdx.x == 64) {      // graph node counts via binary search (batch sorted)
        if (tid < 128) {
            int g = tid;
            int lo = 0, hi = N;
            while (lo < hi) { int m = (lo + hi) >> 1; if (batch[m] <= g) lo = m + 1; else hi = m; }
            int ub = lo;
            lo = 0; hi = N;
            int gm1 = g - 1;
            while (lo < hi) { int m = (lo + hi) >> 1; if (batch[m] <= gm1) lo = m + 1; else hi = m; }
            gcnt[g] = ub - lo;
        }
        return;
    }
    int i = blockIdx.x * 256 + tid;
    int k = i >> 7, c = i & 127;
    float w = W[i];
    int kk = k & 31, k0 = k >> 5;
    int hi = (kk >> 2) & 3;
    int e = (kk & 3) + 4 * (kk >> 4);
    int idx = c * 128 + k0 * 32 + hi * 8 + e;
    Wp[idx ^ ((c & 7) << 3)] = f2b(w);
}

// ---------------- fused BN-finalize + next-W prep + wb + pool finalize ----------------
template <int HASW>
__global__ __launch_bounds__(256) void bn_prep_pool(const float* __restrict__ stats,
                                                    const float* __restrict__ g,
                                                    const float* __restrict__ be,
                                                    const float* __restrict__ W,
                                                    unsigned short* __restrict__ Wp,
                                                    float* __restrict__ wb,
                                                    const float* __restrict__ sseg,
                                                    const int* __restrict__ gcnt,
                                                    float* __restrict__ out,
                                                    int layer, float invN) {
    int tid = threadIdx.x;
    if (HASW && blockIdx.x < 64) {
        __shared__ float scL[128], shL[128];
        if (tid < 128) {
            float mu = stats[tid] * invN;
            float var = stats[128 + tid] * invN - mu * mu;
            float sc = g[tid] * rsqrtf(var + BN_EPS);
            scL[tid] = sc;
            shL[tid] = be[tid] - mu * sc;
        }
        __syncthreads();
        int i = blockIdx.x * 256 + tid;
        int k = i >> 7, c = i & 127;
        float w = W[i] * scL[k];
        int kk = k & 31, k0 = k >> 5;
        int hi = (kk >> 2) & 3;
        int e = (kk & 3) + 4 * (kk >> 4);
        int idx = c * 128 + k0 * 32 + hi * 8 + e;
        Wp[idx ^ ((c & 7) << 3)] = f2b(w);
        if (blockIdx.x == 0 && tid < 128) {
            float acc = 0.f;
#pragma unroll 4
            for (int kx = 0; kx < 128; ++kx) acc = fmaf(shL[kx], W[kx * 128 + tid], acc);
            wb[tid] = acc;
        }
        return;
    }
    int bx = HASW ? (int)blockIdx.x - 64 : (int)blockIdx.x;
    int idx = bx * 256 + tid;   // 64 blocks x 256 = 16384 = 128 graphs x 128 feats
    int d = idx & 127, gr = idx >> 7;
    float mu = stats[d] * invN;
    float var = stats[128 + d] * invN - mu * mu;
    float sc = g[d] * rsqrtf(var + BN_EPS);
    float sh = be[d] - mu * sc;
    out[(size_t)gr * 384 + layer * 128 + d] = sc * sseg[gr * 128 + d] + (float)gcnt[gr] * sh;
}

// ---------------- MFMA GEMM: hW'[N,128](bf16) = dinv * (BN(A) @ W) ----------------
template <int AF32>
__global__ __launch_bounds__(256) void gemm_mfma(const void* __restrict__ Avoid,
                                                 const unsigned short* __restrict__ Wp,
                                                 const float* __restrict__ wb,
                                                 const float* __restrict__ dinv,
                                                 unsigned short* __restrict__ Cb, int N) {
    __shared__ unsigned short sWt[128 * 128];
    int tid = threadIdx.x;
    {
        const uint4* src = (const uint4*)Wp;
        uint4* dst = (uint4*)sWt;
#pragma unroll
        for (int j = 0; j < 8; ++j) dst[tid + 256 * j] = src[tid + 256 * j];
    }
    __syncthreads();

    int wave = tid >> 6, lane = tid & 63;
    int lo4 = lane & 15, hi = lane >> 4;
    int rowBase = blockIdx.x * 128 + wave * 32;

    f32x4 acc[8][2];
#pragma unroll
    for (int ct = 0; ct < 8; ++ct)
#pragma unroll
        for (int rt = 0; rt < 2; ++rt) acc[ct][rt] = (f32x4){0.f, 0.f, 0.f, 0.f};

    const float* Af = (const float*)Avoid;
    const unsigned short* Ab = (const unsigned short*)Avoid;

    for (int k0 = 0; k0 < 128; k0 += 32) {
        bf16x8 bfrag[2];
#pragma unroll
        for (int rt = 0; rt < 2; ++rt) {
            int r = rowBase + rt * 16 + lo4;
            if (r >= N) r = N - 1;
            if (AF32) {
                float4 f0 = *(const float4*)(Af + (size_t)r * 128 + k0 + 4 * hi);
                float4 f1 = *(const float4*)(Af + (size_t)r * 128 + k0 + 16 + 4 * hi);
                bf16x8 f;
                f[0] = (short)f2b(f0.x); f[1] = (short)f2b(f0.y);
                f[2] = (short)f2b(f0.z); f[3] = (short)f2b(f0.w);
                f[4] = (short)f2b(f1.x); f[5] = (short)f2b(f1.y);
                f[6] = (short)f2b(f1.z); f[7] = (short)f2b(f1.w);
                bfrag[rt] = f;
            } else {
                s16x4 a0 = *(const s16x4*)(Ab + (size_t)r * 128 + k0 + 4 * hi);
                s16x4 a1 = *(const s16x4*)(Ab + (size_t)r * 128 + k0 + 16 + 4 * hi);
                bf16x8 f;
                f[0] = a0[0]; f[1] = a0[1]; f[2] = a0[2]; f[3] = a0[3];
                f[4] = a1[0]; f[5] = a1[1]; f[6] = a1[2]; f[7] = a1[3];
                bfrag[rt] = f;
            }
        }
        int kq = k0 >> 5;
#pragma unroll
        for (int ct = 0; ct < 8; ++ct) {
            int c = ct * 16 + lo4;
            int idx = (c * 128 + kq * 32 + hi * 8) ^ ((c & 7) << 3);
            bf16x8 af = *(const bf16x8*)(sWt + idx);
#pragma unroll
            for (int rt = 0; rt < 2; ++rt)
                acc[ct][rt] = __builtin_amdgcn_mfma_f32_16x16x32_bf16(af, bfrag[rt], acc[ct][rt], 0, 0, 0);
        }
    }

#pragma unroll
    for (int rt = 0; rt < 2; ++rt) {
        int r = rowBase + rt * 16 + lo4;
        if (r < N) {
            float dv = dinv[r];
#pragma unroll
            for (int ct = 0; ct < 8; ++ct) {
                int c0 = ct * 16 + hi * 4;
                float4 wbv = make_float4(0.f, 0.f, 0.f, 0.f);
                if (!AF32) wbv = *(const float4*)(wb + c0);
                ushort4 s;
                s.x = f2b((acc[ct][rt][0] + wbv.x) * dv);
                s.y = f2b((acc[ct][rt][1] + wbv.y) * dv);
                s.z = f2b((acc[ct][rt][2] + wbv.z) * dv);
                s.w = f2b((acc[ct][rt][3] + wbv.w) * dv);
                *(ushort4*)(Cb + (size_t)r * 128 + c0) = s;
            }
        }
    }
}

// ---------------- aggregation + bias + relu: one wave per node, 16-edge-deep ILP ----------
__global__ __launch_bounds__(256) void agg_relu_b16(const uint4* __restrict__ hW4,
                                                    const int* __restrict__ rowp,
                                                    const int* __restrict__ cnt,
                                                    const int* __restrict__ csr,
                                                    const float* __restrict__ dinv,
                                                    const float* __restrict__ bias,
                                                    unsigned int* __restrict__ z32, int N) {
    int wave = threadIdx.x >> 6, lane = threadIdx.x & 63;
    int v = blockIdx.x * 4 + wave;
    if (v >= N) return;
    int q = lane >> 4, c = lane & 15;
    int beg = rowp[v];
    int num = cnt[v];
    float s0 = 0.f, s1 = 0.f, s2 = 0.f, s3 = 0.f, s4 = 0.f, s5 = 0.f, s6 = 0.f, s7 = 0.f;
    int i = 0;
    for (; i + 16 <= num; i += 16) {
        int u0 = csr[beg + i + q];
        int u1 = csr[beg + i + 4 + q];
        int u2 = csr[beg + i + 8 + q];
        int u3 = csr[beg + i + 12 + q];
        uint4 p0 = hW4[(size_t)u0 * 16 + c];
        uint4 p1 = hW4[(size_t)u1 * 16 + c];
        uint4 p2 = hW4[(size_t)u2 * 16 + c];
        uint4 p3 = hW4[(size_t)u3 * 16 + c];
        s0 += (b2f_lo(p0.x) + b2f_lo(p1.x)) + (b2f_lo(p2.x) + b2f_lo(p3.x));
        s1 += (b2f_hi(p0.x) + b2f_hi(p1.x)) + (b2f_hi(p2.x) + b2f_hi(p3.x));
        s2 += (b2f_lo(p0.y) + b2f_lo(p1.y)) + (b2f_lo(p2.y) + b2f_lo(p3.y));
        s3 += (b2f_hi(p0.y) + b2f_hi(p1.y)) + (b2f_hi(p2.y) + b2f_hi(p3.y));
        s4 += (b2f_lo(p0.z) + b2f_lo(p1.z)) + (b2f_lo(p2.z) + b2f_lo(p3.z));
        s5 += (b2f_hi(p0.z) + b2f_hi(p1.z)) + (b2f_hi(p2.z) + b2f_hi(p3.z));
        s6 += (b2f_lo(p0.w) + b2f_lo(p1.w)) + (b2f_lo(p2.w) + b2f_lo(p3.w));
        s7 += (b2f_hi(p0.w) + b2f_hi(p1.w)) + (b2f_hi(p2.w) + b2f_hi(p3.w));
    }
    for (; i + 4 <= num; i += 4) {
        int u = csr[beg + i + q];
        uint4 p = hW4[(size_t)u * 16 + c];
        s0 += b2f_lo(p.x); s1 += b2f_hi(p.x);
        s2 += b2f_lo(p.y); s3 += b2f_hi(p.y);
        s4 += b2f_lo(p.z); s5 += b2f_hi(p.z);
        s6 += b2f_lo(p.w); s7 += b2f_hi(p.w);
    }
    if (i < num) {
        int idx = i + q;
        bool ok = idx < num;
        int u = ok ? csr[beg + idx] : v;
        float m = ok ? 1.f : 0.f;
        uint4 p = hW4[(size_t)u * 16 + c];
        s0 = fmaf(m, b2f_lo(p.x), s0);
        s1 = fmaf(m, b2f_hi(p.x), s1);
        s2 = fmaf(m, b2f_lo(p.y), s2);
        s3 = fmaf(m, b2f_hi(p.y), s3);
        s4 = fmaf(m, b2f_lo(p.z), s4);
        s5 = fmaf(m, b2f_hi(p.z), s5);
        s6 = fmaf(m, b2f_lo(p.w), s6);
        s7 = fmaf(m, b2f_hi(p.w), s7);
    }
    s0 += __shfl_xor(s0, 16, 64); s0 += __shfl_xor(s0, 32, 64);
    s1 += __shfl_xor(s1, 16, 64); s1 += __shfl_xor(s1, 32, 64);
    s2 += __shfl_xor(s2, 16, 64); s2 += __shfl_xor(s2, 32, 64);
    s3 += __shfl_xor(s3, 16, 64); s3 += __shfl_xor(s3, 32, 64);
    s4 += __shfl_xor(s4, 16, 64); s4 += __shfl_xor(s4, 32, 64);
    s5 += __shfl_xor(s5, 16, 64); s5 += __shfl_xor(s5, 32, 64);
    s6 += __shfl_xor(s6, 16, 64); s6 += __shfl_xor(s6, 32, 64);
    s7 += __shfl_xor(s7, 16, 64); s7 += __shfl_xor(s7, 32, 64);
    if (q == 0) {
        float dv = dinv[v];
        uint4 pv = hW4[(size_t)v * 16 + c];
        float4 b0 = *(const float4*)(bias + 8 * c);
        float4 b1 = *(const float4*)(bias + 8 * c + 4);
        float r0 = dv * (s0 + b2f_lo(pv.x)) + b0.x;
        float r1 = dv * (s1 + b2f_hi(pv.x)) + b0.y;
        float r2 = dv * (s2 + b2f_lo(pv.y)) + b0.z;
        float r3 = dv * (s3 + b2f_hi(pv.y)) + b0.w;
        float r4 = dv * (s4 + b2f_lo(pv.z)) + b1.x;
        float r5 = dv * (s5 + b2f_hi(pv.z)) + b1.y;
        float r6 = dv * (s6 + b2f_lo(pv.w)) + b1.z;
        float r7 = dv * (s7 + b2f_hi(pv.w)) + b1.w;
        uint4 o;
        o.x = packrelu(r0, r1);
        o.y = packrelu(r2, r3);
        o.z = packrelu(r4, r5);
        o.w = packrelu(r6, r7);
        *(uint4*)(z32 + (size_t)v * 64 + 4 * c) = o;
    }
}

// ---------------- BN statistics + per-graph segment sums (contiguous strips) ----------------
__global__ __launch_bounds__(256) void bn_stats_seg(const unsigned int* __restrict__ z32,
                                                    const int* __restrict__ batch,
                                                    float* __restrict__ stats,
                                                    float* __restrict__ sseg,
                                                    int strip, int N) {
    int lane = threadIdx.x & 63, sub = threadIdx.x >> 6;
    int v0 = blockIdx.x * strip;
    int v1 = min(v0 + strip, N);
    float s0 = 0.f, s1 = 0.f, q0 = 0.f, q1 = 0.f;
    float a0 = 0.f, a1 = 0.f;
    int cur = -1;
    for (int v = v0 + sub; v < v1; v += 4) {
        unsigned int p = z32[(size_t)v * 64 + lane];
        float x0 = b2f_lo(p), x1 = b2f_hi(p);
        s0 += x0; q0 = fmaf(x0, x0, q0);
        s1 += x1; q1 = fmaf(x1, x1, q1);
        int g = batch[v];
        if (g != cur) {
            if (cur >= 0) {
                atomicAdd(&sseg[cur * 128 + 2 * lane], a0);
                atomicAdd(&sseg[cur * 128 + 2 * lane + 1], a1);
            }
            cur = g; a0 = 0.f; a1 = 0.f;
        }
        a0 += x0; a1 += x1;
    }
    if (cur >= 0) {
        atomicAdd(&sseg[cur * 128 + 2 * lane], a0);
        atomicAdd(&sseg[cur * 128 + 2 * lane + 1], a1);
    }
    __shared__ float ls[256][4];
    ls[threadIdx.x][0] = s0; ls[threadIdx.x][1] = s1;
    ls[threadIdx.x][2] = q0; ls[threadIdx.x][3] = q1;
    __syncthreads();
    if (sub == 0) {
        for (int k = 1; k < 4; ++k) {
            s0 += ls[lane + 64 * k][0]; s1 += ls[lane + 64 * k][1];
            q0 += ls[lane + 64 * k][2]; q1 += ls[lane + 64 * k][3];
        }
        atomicAdd(&stats[2 * lane], s0);
        atomicAdd(&stats[2 * lane + 1], s1);
        atomicAdd(&stats[128 + 2 * lane], q0);
        atomicAdd(&stats[129 + 2 * lane], q1);
    }
}

// ---------------- launch ----------------
extern "C" void kernel_launch(void* const* d_in, const int* in_sizes, int n_in,
                              void* d_out, int out_size, void* d_ws, size_t ws_size,
                              hipStream_t stream) {
    const float* x    = (const float*)d_in[0];
    const int* eidx   = (const int*)d_in[1];
    const int* batch  = (const int*)d_in[2];

    const int N = in_sizes[2];          // 50000
    const int E = in_sizes[1] / 2;      // 1600000
    const int* src = eidx;
    const int* dst = eidx + E;

    const int nchunks = (E + CHUNK - 1) / CHUNK;   // 196
    const int NB = (N + 127) / 128;                // 391
    const float invN = 1.0f / N;

    size_t off = 0;
    auto alloc = [&](size_t bytes) {
        void* p = (char*)d_ws + off;
        off += (bytes + 255) & ~(size_t)255;
        return p;
    };
    unsigned short* hWb = (unsigned short*)alloc((size_t)N * 128 * 2);  // bf16 dinv*h@W
    unsigned int* z32   = (unsigned int*)alloc((size_t)N * 64 * 4);     // bf16 post-agg
    unsigned int* bpairs= (unsigned int*)alloc((size_t)nchunks * CHUNK * 4);
    int*   csr   = (int*)alloc((size_t)E * 4);
    int*   cnts  = (int*)alloc((size_t)nchunks * NBU * 4);
    int*   cbase = (int*)alloc((size_t)nchunks * NBU * 4);
    // zeroed region: stats | btot | sseg (contiguous, 256-aligned sizes)
    float* stats = (float*)alloc(3 * 256 * 4);                          // 3072 B
    int*   btot  = (int*)alloc((size_t)NBU * 4);                        // 2048 B
    float* sseg  = (float*)alloc(3 * (size_t)N_GRAPHS * 128 * 4);       // 196608 B
    size_t zero_bytes = (size_t)((char*)sseg - (char*)stats) + 3 * (size_t)N_GRAPHS * 128 * 4;
    int*   degar = (int*)alloc((size_t)N * 4);
    int*   rowp  = (int*)alloc((size_t)N * 4);
    float* dinv  = (float*)alloc((size_t)N * 4);
    float* wbuf  = (float*)alloc(2 * 128 * 4);
    int*   gcnt  = (int*)alloc(N_GRAPHS * 4);
    unsigned short* Wp = (unsigned short*)alloc(128 * 128 * 2);

    float* out = (float*)d_out;

    hipMemsetAsync(stats, 0, zero_bytes, stream);

    bin_chunks<<<nchunks, 512, 0, stream>>>(src, dst, bpairs, cnts, cbase, btot, E);
    bucket_csr<<<NB, 256, 0, stream>>>(bpairs, cnts, cbase, btot, rowp, degar, dinv, csr,
                                       nchunks, N);

    const int gemm_blocks = (N + 127) / 128;   // 391
    const int agg_blocks  = (N + 3) / 4;       // 12500
    const int strip = (N + 255) / 256;         // 196 nodes per bn_stats block

    // W0 prep (no BN fold) + graph counts in block 64
    prep_w0<<<65, 256, 0, stream>>>((const float*)d_in[3], Wp, batch, gcnt, N);

    for (int l = 0; l < 3; ++l) {
        const float* b  = (const float*)d_in[4 + 4 * l];
        const float* g  = (const float*)d_in[5 + 4 * l];
        const float* be = (const float*)d_in[6 + 4 * l];

        if (l == 0)
            gemm_mfma<1><<<gemm_blocks, 256, 0, stream>>>((const void*)x, Wp, nullptr, dinv, hWb, N);
        else
            gemm_mfma<0><<<gemm_blocks, 256, 0, stream>>>((const void*)z32, Wp,
                                                          wbuf + (l - 1) * 128, dinv, hWb, N);

        agg_relu_b16<<<agg_blocks, 256, 0, stream>>>((const uint4*)hWb, rowp, degar, csr,
                                                     dinv, b, z32, N);
        bn_stats_seg<<<256, 256, 0, stream>>>(z32, batch, stats + l * 256,
                                              sseg + (size_t)l * N_GRAPHS * 128, strip, N);
        if (l < 2) {
            bn_prep_pool<1><<<128, 256, 0, stream>>>(stats + l * 256, g, be,
                                                     (const float*)d_in[3 + 4 * (l + 1)],
                                                     Wp, wbuf + l * 128,
                                                     sseg + (size_t)l * N_GRAPHS * 128, gcnt,
                                                     out, l, invN);
        } else {
            bn_prep_pool<0><<<64, 256, 0, stream>>>(stats + l * 256, g, be, nullptr,
                                                    nullptr, nullptr,
                                                    sseg + (size_t)l * N_GRAPHS * 128, gcnt,
                                                    out, l, invN);
        }
    }
}

// Round 12
// 422.091 us; speedup vs baseline: 1.0321x; 1.0321x over previous
//
#include <hip/hip_runtime.h>
#include <hip/hip_bf16.h>

#define N_GRAPHS 128
#define BN_EPS 1e-5f
#define CHUNK 8192
#define NBU 512            // padded bucket count (actual NB = ceil(N/128) = 391)
#define CAP 8192           // per-bucket edge capacity (mean 4096, sd ~64)

typedef short bf16x8 __attribute__((ext_vector_type(8)));
typedef short s16x4 __attribute__((ext_vector_type(4)));
typedef float f32x4 __attribute__((ext_vector_type(4)));

__device__ __forceinline__ unsigned short f2b(float f) {   // f32 -> bf16 RNE
    unsigned int u = __builtin_bit_cast(unsigned int, f);
    u += 0x7FFFu + ((u >> 16) & 1u);
    return (unsigned short)(u >> 16);
}
__device__ __forceinline__ float b2f_lo(unsigned int p) {
    return __builtin_bit_cast(float, p << 16);
}
__device__ __forceinline__ float b2f_hi(unsigned int p) {
    return __builtin_bit_cast(float, p & 0xFFFF0000u);
}
__device__ __forceinline__ unsigned int packrelu(float a, float b) {
    return (unsigned int)f2b(fmaxf(a, 0.f)) | ((unsigned int)f2b(fmaxf(b, 0.f)) << 16);
}

// ---------------- K1: per-chunk bucket binning + W0 prep + graph counts ----------------
// blocks [0, nchunks): bin edges; [nchunks, nchunks+32): W0 bf16 swizzle prep;
// block nchunks+32: per-graph node counts.
__global__ __launch_bounds__(512) void bin_chunks(const int* __restrict__ src,
                                                  const int* __restrict__ dst,
                                                  unsigned int* __restrict__ bpairs,
                                                  int* __restrict__ cnts,
                                                  int* __restrict__ cbase,
                                                  int* __restrict__ btot,
                                                  const float* __restrict__ W0,
                                                  unsigned short* __restrict__ Wp,
                                                  const int* __restrict__ batch,
                                                  int* __restrict__ gcnt,
                                                  int nchunks, int N, int E) {
    __shared__ int lhist[NBU], lscan[NBU], lfill[NBU];
    int tid = threadIdx.x;
    int blk = blockIdx.x;
    if (blk >= nchunks) {
        int role = blk - nchunks;
        if (role < 32) {               // W0 prep: 32 blocks x 512 = 16384
            int i = role * 512 + tid;
            int k = i >> 7, c = i & 127;
            float w = W0[i];
            int kk = k & 31, k0 = k >> 5;
            int hi = (kk >> 2) & 3;
            int e = (kk & 3) + 4 * (kk >> 4);
            int idx = c * 128 + k0 * 32 + hi * 8 + e;
            Wp[idx ^ ((c & 7) << 3)] = f2b(w);
        } else if (tid < 128) {        // graph counts via binary search (batch sorted)
            int g = tid;
            int lo = 0, hi = N;
            while (lo < hi) { int m = (lo + hi) >> 1; if (batch[m] <= g) lo = m + 1; else hi = m; }
            int ub = lo;
            lo = 0; hi = N;
            int gm1 = g - 1;
            while (lo < hi) { int m = (lo + hi) >> 1; if (batch[m] <= gm1) lo = m + 1; else hi = m; }
            gcnt[g] = ub - lo;
        }
        return;
    }
    int c0 = blk * CHUNK;
    int ecnt = min(CHUNK, E - c0);
    lhist[tid] = 0;
    __syncthreads();
    for (int i = tid; i < ecnt; i += 512)
        atomicAdd(&lhist[((unsigned)dst[c0 + i]) >> 7], 1);
    __syncthreads();
    int orig = lhist[tid];
    atomicAdd(&btot[tid], orig);
    lscan[tid] = orig;
    __syncthreads();
    for (int off = 1; off < NBU; off <<= 1) {
        int t = (tid >= off) ? lscan[tid - off] : 0;
        __syncthreads();
        lscan[tid] += t;
        __syncthreads();
    }
    int excl = lscan[tid] - orig;
    cnts[blk * NBU + tid] = orig;
    cbase[blk * NBU + tid] = excl;
    lfill[tid] = 0;
    __syncthreads();
    lscan[tid] = excl;
    __syncthreads();
    for (int i = tid; i < ecnt; i += 512) {
        int d = dst[c0 + i], s = src[c0 + i];
        int b = ((unsigned)d) >> 7;
        int pos = lscan[b] + atomicAdd(&lfill[b], 1);
        bpairs[c0 + pos] = ((unsigned)(d & 127) << 25) | (unsigned)s;
    }
}

// ---------------- K2: per-bucket CSR finalize (direct global scatter) ----------------
__global__ __launch_bounds__(256) void bucket_csr(const unsigned int* __restrict__ bpairs,
                                                  const int* __restrict__ cnts,
                                                  const int* __restrict__ cbase,
                                                  const int* __restrict__ btot,
                                                  int* __restrict__ rowp,
                                                  int* __restrict__ degarr,
                                                  float* __restrict__ dinv,
                                                  int* __restrict__ csr,
                                                  int nchunks, int N) {
    __shared__ unsigned int lpr[CAP];
    __shared__ int ccnt[256], cofs[256], cb[256];
    __shared__ int lhist[128], lofs[128], lfill[128];
    __shared__ int rsum[256];
    int tid = threadIdx.x;
    int b = blockIdx.x;

    int t1 = (tid < b) ? btot[tid] : 0;
    int t2 = (tid + 256 < b) ? btot[tid + 256] : 0;
    rsum[tid] = t1 + t2;
    __syncthreads();
    for (int off2 = 128; off2 > 0; off2 >>= 1) {
        if (tid < off2) rsum[tid] += rsum[tid + off2];
        __syncthreads();
    }
    int bb = rsum[0];
    int total = btot[b];
    if (total > CAP) total = CAP;
    __syncthreads();

    ccnt[tid] = (tid < nchunks) ? cnts[tid * NBU + b] : 0;
    cb[tid]   = (tid < nchunks) ? cbase[tid * NBU + b] : 0;
    cofs[tid] = ccnt[tid];
    __syncthreads();
    int orig = cofs[tid];
    for (int off = 1; off < 256; off <<= 1) {
        int t = (tid >= off) ? cofs[tid - off] : 0;
        __syncthreads();
        cofs[tid] += t;
        __syncthreads();
    }
    int o = cofs[tid] - orig;
    if (tid < nchunks) {
        int len = ccnt[tid];
        const unsigned int* p = bpairs + (size_t)tid * CHUNK + cb[tid];
        for (int i = 0; i < len; ++i) {
            int q = o + i;
            if (q < CAP) lpr[q] = p[i];
        }
    }
    if (tid < 128) { lhist[tid] = 0; lfill[tid] = 0; }
    __syncthreads();
    for (int i = tid; i < total; i += 256)
        atomicAdd(&lhist[lpr[i] >> 25], 1);
    __syncthreads();
    if (tid < 128) lofs[tid] = lhist[tid];
    __syncthreads();
    for (int off = 1; off < 128; off <<= 1) {
        int t = 0;
        if (tid < 128 && tid >= off) t = lofs[tid - off];
        __syncthreads();
        if (tid < 128) lofs[tid] += t;
        __syncthreads();
    }
    if (tid < 128) {
        int v = b * 128 + tid;
        if (v < N) {
            int dg = lhist[tid];
            degarr[v] = dg;
            rowp[v] = bb + lofs[tid] - dg;
            dinv[v] = rsqrtf((float)(dg + 1));
        }
    }
    __syncthreads();
    for (int i = tid; i < total; i += 256) {
        unsigned int pr = lpr[i];
        int dl = pr >> 25;
        int pos = lofs[dl] - lhist[dl] + atomicAdd(&lfill[dl], 1);
        if (pos < CAP) csr[bb + pos] = (int)(pr & 0x1FFFFFFu);
    }
}

// ---------------- fused BN-finalize + next-W prep + wb + pool finalize ----------------
template <int HASW>
__global__ __launch_bounds__(256) void bn_prep_pool(const float* __restrict__ stats,
                                                    const float* __restrict__ g,
                                                    const float* __restrict__ be,
                                                    const float* __restrict__ W,
                                                    unsigned short* __restrict__ Wp,
                                                    float* __restrict__ wb,
                                                    const float* __restrict__ sseg,
                                                    const int* __restrict__ gcnt,
                                                    float* __restrict__ out,
                                                    int layer, float invN) {
    int tid = threadIdx.x;
    if (HASW && blockIdx.x < 64) {
        __shared__ float scL[128], shL[128];
        if (tid < 128) {
            float mu = stats[tid] * invN;
            float var = stats[128 + tid] * invN - mu * mu;
            float sc = g[tid] * rsqrtf(var + BN_EPS);
            scL[tid] = sc;
            shL[tid] = be[tid] - mu * sc;
        }
        __syncthreads();
        int i = blockIdx.x * 256 + tid;
        int k = i >> 7, c = i & 127;
        float w = W[i] * scL[k];
        int kk = k & 31, k0 = k >> 5;
        int hi = (kk >> 2) & 3;
        int e = (kk & 3) + 4 * (kk >> 4);
        int idx = c * 128 + k0 * 32 + hi * 8 + e;
        Wp[idx ^ ((c & 7) << 3)] = f2b(w);
        if (blockIdx.x == 0 && tid < 128) {
            float acc = 0.f;
#pragma unroll 4
            for (int kx = 0; kx < 128; ++kx) acc = fmaf(shL[kx], W[kx * 128 + tid], acc);
            wb[tid] = acc;
        }
        return;
    }
    int bx = HASW ? (int)blockIdx.x - 64 : (int)blockIdx.x;
    int idx = bx * 256 + tid;   // 64 blocks x 256 = 16384 = 128 graphs x 128 feats
    int d = idx & 127, gr = idx >> 7;
    float mu = stats[d] * invN;
    float var = stats[128 + d] * invN - mu * mu;
    float sc = g[d] * rsqrtf(var + BN_EPS);
    float sh = be[d] - mu * sc;
    out[(size_t)gr * 384 + layer * 128 + d] = sc * sseg[gr * 128 + d] + (float)gcnt[gr] * sh;
}

// ---------------- MFMA GEMM: hW'[N,128](bf16) = dinv * (BN(A) @ W) ----------------
// 256 rows/block, 4 waves x 64 rows; rt=4 so each LDS af fragment feeds 4 MFMAs.
template <int AF32>
__global__ __launch_bounds__(256) void gemm_mfma(const void* __restrict__ Avoid,
                                                 const unsigned short* __restrict__ Wp,
                                                 const float* __restrict__ wb,
                                                 const float* __restrict__ dinv,
                                                 unsigned short* __restrict__ Cb, int N) {
    __shared__ unsigned short sWt[128 * 128];
    int tid = threadIdx.x;
    {
        const uint4* src = (const uint4*)Wp;
        uint4* dst = (uint4*)sWt;
#pragma unroll
        for (int j = 0; j < 8; ++j) dst[tid + 256 * j] = src[tid + 256 * j];
    }
    __syncthreads();

    int wave = tid >> 6, lane = tid & 63;
    int lo4 = lane & 15, hi = lane >> 4;
    int rowBase = blockIdx.x * 256 + wave * 64;

    f32x4 acc[8][4];
#pragma unroll
    for (int ct = 0; ct < 8; ++ct)
#pragma unroll
        for (int rt = 0; rt < 4; ++rt) acc[ct][rt] = (f32x4){0.f, 0.f, 0.f, 0.f};

    const float* Af = (const float*)Avoid;
    const unsigned short* Ab = (const unsigned short*)Avoid;

    for (int k0 = 0; k0 < 128; k0 += 32) {
        bf16x8 bfrag[4];
#pragma unroll
        for (int rt = 0; rt < 4; ++rt) {
            int r = rowBase + rt * 16 + lo4;
            if (r >= N) r = N - 1;
            if (AF32) {
                float4 f0 = *(const float4*)(Af + (size_t)r * 128 + k0 + 4 * hi);
                float4 f1 = *(const float4*)(Af + (size_t)r * 128 + k0 + 16 + 4 * hi);
                bf16x8 f;
                f[0] = (short)f2b(f0.x); f[1] = (short)f2b(f0.y);
                f[2] = (short)f2b(f0.z); f[3] = (short)f2b(f0.w);
                f[4] = (short)f2b(f1.x); f[5] = (short)f2b(f1.y);
                f[6] = (short)f2b(f1.z); f[7] = (short)f2b(f1.w);
                bfrag[rt] = f;
            } else {
                s16x4 a0 = *(const s16x4*)(Ab + (size_t)r * 128 + k0 + 4 * hi);
                s16x4 a1 = *(const s16x4*)(Ab + (size_t)r * 128 + k0 + 16 + 4 * hi);
                bf16x8 f;
                f[0] = a0[0]; f[1] = a0[1]; f[2] = a0[2]; f[3] = a0[3];
                f[4] = a1[0]; f[5] = a1[1]; f[6] = a1[2]; f[7] = a1[3];
                bfrag[rt] = f;
            }
        }
        int kq = k0 >> 5;
#pragma unroll
        for (int ct = 0; ct < 8; ++ct) {
            int c = ct * 16 + lo4;
            int idx = (c * 128 + kq * 32 + hi * 8) ^ ((c & 7) << 3);
            bf16x8 af = *(const bf16x8*)(sWt + idx);
#pragma unroll
            for (int rt = 0; rt < 4; ++rt)
                acc[ct][rt] = __builtin_amdgcn_mfma_f32_16x16x32_bf16(af, bfrag[rt], acc[ct][rt], 0, 0, 0);
        }
    }

#pragma unroll
    for (int rt = 0; rt < 4; ++rt) {
        int r = rowBase + rt * 16 + lo4;
        if (r < N) {
            float dv = dinv[r];
#pragma unroll
            for (int ct = 0; ct < 8; ++ct) {
                int c0 = ct * 16 + hi * 4;
                float4 wbv = make_float4(0.f, 0.f, 0.f, 0.f);
                if (!AF32) wbv = *(const float4*)(wb + c0);
                ushort4 s;
                s.x = f2b((acc[ct][rt][0] + wbv.x) * dv);
                s.y = f2b((acc[ct][rt][1] + wbv.y) * dv);
                s.z = f2b((acc[ct][rt][2] + wbv.z) * dv);
                s.w = f2b((acc[ct][rt][3] + wbv.w) * dv);
                *(ushort4*)(Cb + (size_t)r * 128 + c0) = s;
            }
        }
    }
}

// ---------------- aggregation + bias + relu: one wave per node, 16-edge-deep ILP ----------
__global__ __launch_bounds__(256) void agg_relu_b16(const uint4* __restrict__ hW4,
                                                    const int* __restrict__ rowp,
                                                    const int* __restrict__ cnt,
                                                    const int* __restrict__ csr,
                                                    const float* __restrict__ dinv,
                                                    const float* __restrict__ bias,
                                                    unsigned int* __restrict__ z32, int N) {
    int wave = threadIdx.x >> 6, lane = threadIdx.x & 63;
    int v = blockIdx.x * 4 + wave;
    if (v >= N) return;
    int q = lane >> 4, c = lane & 15;
    int beg = rowp[v];
    int num = cnt[v];
    float s0 = 0.f, s1 = 0.f, s2 = 0.f, s3 = 0.f, s4 = 0.f, s5 = 0.f, s6 = 0.f, s7 = 0.f;
    int i = 0;
    for (; i + 16 <= num; i += 16) {
        int u0 = csr[beg + i + q];
        int u1 = csr[beg + i + 4 + q];
        int u2 = csr[beg + i + 8 + q];
        int u3 = csr[beg + i + 12 + q];
        uint4 p0 = hW4[(size_t)u0 * 16 + c];
        uint4 p1 = hW4[(size_t)u1 * 16 + c];
        uint4 p2 = hW4[(size_t)u2 * 16 + c];
        uint4 p3 = hW4[(size_t)u3 * 16 + c];
        s0 += (b2f_lo(p0.x) + b2f_lo(p1.x)) + (b2f_lo(p2.x) + b2f_lo(p3.x));
        s1 += (b2f_hi(p0.x) + b2f_hi(p1.x)) + (b2f_hi(p2.x) + b2f_hi(p3.x));
        s2 += (b2f_lo(p0.y) + b2f_lo(p1.y)) + (b2f_lo(p2.y) + b2f_lo(p3.y));
        s3 += (b2f_hi(p0.y) + b2f_hi(p1.y)) + (b2f_hi(p2.y) + b2f_hi(p3.y));
        s4 += (b2f_lo(p0.z) + b2f_lo(p1.z)) + (b2f_lo(p2.z) + b2f_lo(p3.z));
        s5 += (b2f_hi(p0.z) + b2f_hi(p1.z)) + (b2f_hi(p2.z) + b2f_hi(p3.z));
        s6 += (b2f_lo(p0.w) + b2f_lo(p1.w)) + (b2f_lo(p2.w) + b2f_lo(p3.w));
        s7 += (b2f_hi(p0.w) + b2f_hi(p1.w)) + (b2f_hi(p2.w) + b2f_hi(p3.w));
    }
    for (; i + 4 <= num; i += 4) {
        int u = csr[beg + i + q];
        uint4 p = hW4[(size_t)u * 16 + c];
        s0 += b2f_lo(p.x); s1 += b2f_hi(p.x);
        s2 += b2f_lo(p.y); s3 += b2f_hi(p.y);
        s4 += b2f_lo(p.z); s5 += b2f_hi(p.z);
        s6 += b2f_lo(p.w); s7 += b2f_hi(p.w);
    }
    if (i < num) {
        int idx = i + q;
        bool ok = idx < num;
        int u = ok ? csr[beg + idx] : v;
        float m = ok ? 1.f : 0.f;
        uint4 p = hW4[(size_t)u * 16 + c];
        s0 = fmaf(m, b2f_lo(p.x), s0);
        s1 = fmaf(m, b2f_hi(p.x), s1);
        s2 = fmaf(m, b2f_lo(p.y), s2);
        s3 = fmaf(m, b2f_hi(p.y), s3);
        s4 = fmaf(m, b2f_lo(p.z), s4);
        s5 = fmaf(m, b2f_hi(p.z), s5);
        s6 = fmaf(m, b2f_lo(p.w), s6);
        s7 = fmaf(m, b2f_hi(p.w), s7);
    }
    s0 += __shfl_xor(s0, 16, 64); s0 += __shfl_xor(s0, 32, 64);
    s1 += __shfl_xor(s1, 16, 64); s1 += __shfl_xor(s1, 32, 64);
    s2 += __shfl_xor(s2, 16, 64); s2 += __shfl_xor(s2, 32, 64);
    s3 += __shfl_xor(s3, 16, 64); s3 += __shfl_xor(s3, 32, 64);
    s4 += __shfl_xor(s4, 16, 64); s4 += __shfl_xor(s4, 32, 64);
    s5 += __shfl_xor(s5, 16, 64); s5 += __shfl_xor(s5, 32, 64);
    s6 += __shfl_xor(s6, 16, 64); s6 += __shfl_xor(s6, 32, 64);
    s7 += __shfl_xor(s7, 16, 64); s7 += __shfl_xor(s7, 32, 64);
    if (q == 0) {
        float dv = dinv[v];
        uint4 pv = hW4[(size_t)v * 16 + c];
        float4 b0 = *(const float4*)(bias + 8 * c);
        float4 b1 = *(const float4*)(bias + 8 * c + 4);
        float r0 = dv * (s0 + b2f_lo(pv.x)) + b0.x;
        float r1 = dv * (s1 + b2f_hi(pv.x)) + b0.y;
        float r2 = dv * (s2 + b2f_lo(pv.y)) + b0.z;
        float r3 = dv * (s3 + b2f_hi(pv.y)) + b0.w;
        float r4 = dv * (s4 + b2f_lo(pv.z)) + b1.x;
        float r5 = dv * (s5 + b2f_hi(pv.z)) + b1.y;
        float r6 = dv * (s6 + b2f_lo(pv.w)) + b1.z;
        float r7 = dv * (s7 + b2f_hi(pv.w)) + b1.w;
        uint4 o;
        o.x = packrelu(r0, r1);
        o.y = packrelu(r2, r3);
        o.z = packrelu(r4, r5);
        o.w = packrelu(r6, r7);
        *(uint4*)(z32 + (size_t)v * 64 + 4 * c) = o;
    }
}

// ---------------- BN statistics + per-graph segment sums (contiguous strips) ----------------
__global__ __launch_bounds__(256) void bn_stats_seg(const unsigned int* __restrict__ z32,
                                                    const int* __restrict__ batch,
                                                    float* __restrict__ stats,
                                                    float* __restrict__ sseg,
                                                    int strip, int N) {
    int lane = threadIdx.x & 63, sub = threadIdx.x >> 6;
    int v0 = blockIdx.x * strip;
    int v1 = min(v0 + strip, N);
    float s0 = 0.f, s1 = 0.f, q0 = 0.f, q1 = 0.f;
    float a0 = 0.f, a1 = 0.f;
    int cur = -1;
    for (int v = v0 + sub; v < v1; v += 4) {
        unsigned int p = z32[(size_t)v * 64 + lane];
        float x0 = b2f_lo(p), x1 = b2f_hi(p);
        s0 += x0; q0 = fmaf(x0, x0, q0);
        s1 += x1; q1 = fmaf(x1, x1, q1);
        int g = batch[v];
        if (g != cur) {
            if (cur >= 0) {
                atomicAdd(&sseg[cur * 128 + 2 * lane], a0);
                atomicAdd(&sseg[cur * 128 + 2 * lane + 1], a1);
            }
            cur = g; a0 = 0.f; a1 = 0.f;
        }
        a0 += x0; a1 += x1;
    }
    if (cur >= 0) {
        atomicAdd(&sseg[cur * 128 + 2 * lane], a0);
        atomicAdd(&sseg[cur * 128 + 2 * lane + 1], a1);
    }
    __shared__ float ls[256][4];
    ls[threadIdx.x][0] = s0; ls[threadIdx.x][1] = s1;
    ls[threadIdx.x][2] = q0; ls[threadIdx.x][3] = q1;
    __syncthreads();
    if (sub == 0) {
        for (int k = 1; k < 4; ++k) {
            s0 += ls[lane + 64 * k][0]; s1 += ls[lane + 64 * k][1];
            q0 += ls[lane + 64 * k][2]; q1 += ls[lane + 64 * k][3];
        }
        atomicAdd(&stats[2 * lane], s0);
        atomicAdd(&stats[2 * lane + 1], s1);
        atomicAdd(&stats[128 + 2 * lane], q0);
        atomicAdd(&stats[129 + 2 * lane], q1);
    }
}

// ---------------- launch ----------------
extern "C" void kernel_launch(void* const* d_in, const int* in_sizes, int n_in,
                              void* d_out, int out_size, void* d_ws, size_t ws_size,
                              hipStream_t stream) {
    const float* x    = (const float*)d_in[0];
    const int* eidx   = (const int*)d_in[1];
    const int* batch  = (const int*)d_in[2];

    const int N = in_sizes[2];          // 50000
    const int E = in_sizes[1] / 2;      // 1600000
    const int* src = eidx;
    const int* dst = eidx + E;

    const int nchunks = (E + CHUNK - 1) / CHUNK;   // 196
    const int NB = (N + 127) / 128;                // 391
    const float invN = 1.0f / N;

    size_t off = 0;
    auto alloc = [&](size_t bytes) {
        void* p = (char*)d_ws + off;
        off += (bytes + 255) & ~(size_t)255;
        return p;
    };
    unsigned short* hWb = (unsigned short*)alloc((size_t)N * 128 * 2);  // bf16 dinv*h@W
    unsigned int* z32   = (unsigned int*)alloc((size_t)N * 64 * 4);     // bf16 post-agg
    unsigned int* bpairs= (unsigned int*)alloc((size_t)nchunks * CHUNK * 4);
    int*   csr   = (int*)alloc((size_t)E * 4);
    int*   cnts  = (int*)alloc((size_t)nchunks * NBU * 4);
    int*   cbase = (int*)alloc((size_t)nchunks * NBU * 4);
    // zeroed region: stats | btot | sseg (contiguous, 256-aligned sizes)
    float* stats = (float*)alloc(3 * 256 * 4);                          // 3072 B
    int*   btot  = (int*)alloc((size_t)NBU * 4);                        // 2048 B
    float* sseg  = (float*)alloc(3 * (size_t)N_GRAPHS * 128 * 4);       // 196608 B
    size_t zero_bytes = (size_t)((char*)sseg - (char*)stats) + 3 * (size_t)N_GRAPHS * 128 * 4;
    int*   degar = (int*)alloc((size_t)N * 4);
    int*   rowp  = (int*)alloc((size_t)N * 4);
    float* dinv  = (float*)alloc((size_t)N * 4);
    float* wbuf  = (float*)alloc(2 * 128 * 4);
    int*   gcnt  = (int*)alloc(N_GRAPHS * 4);
    unsigned short* Wp = (unsigned short*)alloc(128 * 128 * 2);

    float* out = (float*)d_out;

    hipMemsetAsync(stats, 0, zero_bytes, stream);

    // binning + W0 prep + graph counts in one launch
    bin_chunks<<<nchunks + 33, 512, 0, stream>>>(src, dst, bpairs, cnts, cbase, btot,
                                                 (const float*)d_in[3], Wp, batch, gcnt,
                                                 nchunks, N, E);
    bucket_csr<<<NB, 256, 0, stream>>>(bpairs, cnts, cbase, btot, rowp, degar, dinv, csr,
                                       nchunks, N);

    const int gemm_blocks = (N + 255) / 256;   // 196 (256 rows/block, rt=4)
    const int agg_blocks  = (N + 3) / 4;       // 12500
    const int strip = (N + 255) / 256;         // 196 nodes per bn_stats block

    for (int l = 0; l < 3; ++l) {
        const float* b  = (const float*)d_in[4 + 4 * l];
        const float* g  = (const float*)d_in[5 + 4 * l];
        const float* be = (const float*)d_in[6 + 4 * l];

        if (l == 0)
            gemm_mfma<1><<<gemm_blocks, 256, 0, stream>>>((const void*)x, Wp, nullptr, dinv, hWb, N);
        else
            gemm_mfma<0><<<gemm_blocks, 256, 0, stream>>>((const void*)z32, Wp,
                                                          wbuf + (l - 1) * 128, dinv, hWb, N);

        agg_relu_b16<<<agg_blocks, 256, 0, stream>>>((const uint4*)hWb, rowp, degar, csr,
                                                     dinv, b, z32, N);
        bn_stats_seg<<<256, 256, 0, stream>>>(z32, batch, stats + l * 256,
                                              sseg + (size_t)l * N_GRAPHS * 128, strip, N);
        if (l < 2) {
            bn_prep_pool<1><<<128, 256, 0, stream>>>(stats + l * 256, g, be,
                                                     (const float*)d_in[3 + 4 * (l + 1)],
                                                     Wp, wbuf + l * 128,
                                                     sseg + (size_t)l * N_GRAPHS * 128, gcnt,
                                                     out, l, invN);
        } else {
            bn_prep_pool<0><<<64, 256, 0, stream>>>(stats + l * 256, g, be, nullptr,
                                                    nullptr, nullptr,
                                                    sseg + (size_t)l * N_GRAPHS * 128, gcnt,
                                                    out, l, invN);
        }
    }
}